// Round 4
// baseline (130.600 us; speedup 1.0000x reference)
//
#include <hip/hip_runtime.h>
#include <math.h>

#define S_LEN 2048
#define B_TOT 4096
#define CHUNK 16                  // steps per thread; 128 threads (2 waves) per batch
#define PH_STEPS 2                // steps per phase
#define N_PH (CHUNK / PH_STEPS)   // 8 phases
constexpr float DT       = 1.0f / 200.0f;
constexpr float HALF_DT2 = DT * DT * 0.5f;

// One preintegration step applied to running segment state (R,V,P).
__device__ __forceinline__ void istep(
    float& R00, float& R01, float& R02,
    float& R10, float& R11, float& R12,
    float& R20, float& R21, float& R22,
    float& Vx, float& Vy, float& Vz,
    float& Px, float& Py, float& Pz,
    float wx, float wy, float wz, float ax, float ay, float az)
{
    const float ux = wx * DT, uy = wy * DT, uz = wz * DT;
    const float t2 = ux * ux + uy * uy + uz * uz;          // theta^2 (tiny)
    const float Ac = 1.0f + t2 * (-1.0f / 6.0f  + t2 * (1.0f / 120.0f));
    const float Bc = 0.5f + t2 * (-1.0f / 24.0f + t2 * (1.0f / 720.0f));

    const float K00 = 1.0f + Bc * (ux * ux - t2);
    const float K11 = 1.0f + Bc * (uy * uy - t2);
    const float K22 = 1.0f + Bc * (uz * uz - t2);
    const float bxy = Bc * ux * uy, bxz = Bc * ux * uz, byz = Bc * uy * uz;
    const float aux = Ac * ux, auy = Ac * uy, auz = Ac * uz;
    const float K01 = bxy - auz, K10 = bxy + auz;
    const float K02 = bxz + auy, K20 = bxz - auy;
    const float K12 = byz - aux, K21 = byz + aux;

    float r0, r1, r2;
    r0 = R00 * K00 + R01 * K10 + R02 * K20;
    r1 = R00 * K01 + R01 * K11 + R02 * K21;
    r2 = R00 * K02 + R01 * K12 + R02 * K22;
    R00 = r0; R01 = r1; R02 = r2;
    r0 = R10 * K00 + R11 * K10 + R12 * K20;
    r1 = R10 * K01 + R11 * K11 + R12 * K21;
    r2 = R10 * K02 + R11 * K12 + R12 * K22;
    R10 = r0; R11 = r1; R12 = r2;
    r0 = R20 * K00 + R21 * K10 + R22 * K20;
    r1 = R20 * K01 + R21 * K11 + R22 * K21;
    r2 = R20 * K02 + R21 * K12 + R22 * K22;
    R20 = r0; R21 = r1; R22 = r2;

    const float tx = R00 * ax + R01 * ay + R02 * az;
    const float ty = R10 * ax + R11 * ay + R12 * az;
    const float tz = R20 * ax + R21 * ay + R22 * az;
    Vx += tx * DT; Vy += ty * DT; Vz += tz * DT;
    Px += Vx * DT + tx * HALF_DT2;
    Py += Vy * DT + ty * HALF_DT2;
    Pz += Vz * DT + tz * HALF_DT2;
}

__device__ __forceinline__ void gload16(const float4* g, float4* l)
{
    // async global -> LDS, 16B per lane; LDS dest = wave-uniform base + lane*16
    __builtin_amdgcn_global_load_lds(
        (const __attribute__((address_space(1))) void*)g,
        (__attribute__((address_space(3))) void*)l,
        16, 0, 0);
}

// block = 256 threads = 4 waves = 2 batches (2 waves per batch).
// __launch_bounds__(256, 8): VGPR cap 64 -> 8 waves/SIMD. Live set ~50 regs
// (state 15 + 3 float4 phase regs + 3 src pointers) thanks to global_load_lds
// eliminating prefetch registers. LDS 12.4 KB/block -> 8 blocks/CU fits.
__global__ __launch_bounds__(256, 8)
void preint_kernel(const float* __restrict__ in, float* __restrict__ out)
{
    const int slot = threadIdx.x >> 7;             // batch within block (0..1)
    const int b    = blockIdx.x * 2 + slot;
    const int tid  = threadIdx.x & 127;            // thread within batch
    const int lane = threadIdx.x & 63;
    const int half = (threadIdx.x >> 6) & 1;       // which wave of the batch
    const int wv   = threadIdx.x >> 6;             // wave within block (0..3)

    // Per-wave staging buffer: 192 float4 slots (3 KiB), single-buffered.
    // Slot s holds record (s/3)'s float4 #(s%3) of the current phase, so
    // record r's data sits at byte offset r*48 — stride 48 = odd*16 makes the
    // per-lane ds_read_b128 transpose bank-conflict-free.
    __shared__ float4 lds[4][192];
    __shared__ float stx[2][15];                   // cross-wave combine

    // gather source pointers: gload instruction m (0..2), this lane fills
    // slot s = m*64+lane -> record lr=s/3 piece j=s%3;
    // global float4 index = (half*64+lr)*24 + p*3 + j
    const float4* g4 = reinterpret_cast<const float4*>(in) + (size_t)b * (S_LEN * 6 / 4);
    const float4* gp0, *gp1, *gp2;
    {
        const int s0 = lane,      lr0 = s0 / 3, j0 = s0 - 3 * lr0;
        const int s1 = 64 + lane, lr1 = s1 / 3, j1 = s1 - 3 * lr1;
        const int s2 = 128 + lane,lr2 = s2 / 3, j2 = s2 - 3 * lr2;
        gp0 = g4 + (half * 64 + lr0) * 24 + j0;
        gp1 = g4 + (half * 64 + lr1) * 24 + j1;
        gp2 = g4 + (half * 64 + lr2) * 24 + j2;
    }

    // prologue: stage phase 0
    gload16(gp0, &lds[wv][0]);
    gload16(gp1, &lds[wv][64]);
    gload16(gp2, &lds[wv][128]);

    float R00 = 1.f, R01 = 0.f, R02 = 0.f;
    float R10 = 0.f, R11 = 1.f, R12 = 0.f;
    float R20 = 0.f, R21 = 0.f, R22 = 1.f;
    float Vx = 0.f, Vy = 0.f, Vz = 0.f;
    float Px = 0.f, Py = 0.f, Pz = 0.f;

    const int rbase = lane * 3;

    #pragma unroll 1
    for (int p = 0; p < N_PH; ++p) {
        // wait for this phase's staged data to land in LDS
        asm volatile("s_waitcnt vmcnt(0)" ::: "memory");
        const float4 q0 = lds[wv][rbase];
        const float4 q1 = lds[wv][rbase + 1];
        const float4 q2 = lds[wv][rbase + 2];
        // drain ds_reads, then overwrite the buffer with next phase's loads
        asm volatile("s_waitcnt lgkmcnt(0)" ::: "memory");
        if (p < N_PH - 1) {
            gp0 += 3; gp1 += 3; gp2 += 3;
            gload16(gp0, &lds[wv][0]);
            gload16(gp1, &lds[wv][64]);
            gload16(gp2, &lds[wv][128]);
        }

        istep(R00,R01,R02,R10,R11,R12,R20,R21,R22,Vx,Vy,Vz,Px,Py,Pz,
              q0.x, q0.y, q0.z, q0.w, q1.x, q1.y);
        istep(R00,R01,R02,R10,R11,R12,R20,R21,R22,Vx,Vy,Vz,Px,Py,Pz,
              q1.z, q1.w, q2.x, q2.y, q2.z, q2.w);
    }

    // ordered tree reduction across the wave: lane i holds chunks [i, i+o)
    #pragma unroll
    for (int o = 1; o < 64; o <<= 1) {
        const float Tb = (float)(o * CHUNK) * DT;
        const float S00 = __shfl_down(R00, o, 64), S01 = __shfl_down(R01, o, 64), S02 = __shfl_down(R02, o, 64);
        const float S10 = __shfl_down(R10, o, 64), S11 = __shfl_down(R11, o, 64), S12 = __shfl_down(R12, o, 64);
        const float S20 = __shfl_down(R20, o, 64), S21 = __shfl_down(R21, o, 64), S22 = __shfl_down(R22, o, 64);
        const float Wx  = __shfl_down(Vx, o, 64),  Wy  = __shfl_down(Vy, o, 64),  Wz  = __shfl_down(Vz, o, 64);
        const float Qx  = __shfl_down(Px, o, 64),  Qy  = __shfl_down(Py, o, 64),  Qz  = __shfl_down(Pz, o, 64);

        const float nPx = Px + Vx * Tb + R00 * Qx + R01 * Qy + R02 * Qz;
        const float nPy = Py + Vy * Tb + R10 * Qx + R11 * Qy + R12 * Qz;
        const float nPz = Pz + Vz * Tb + R20 * Qx + R21 * Qy + R22 * Qz;
        const float nVx = Vx + R00 * Wx + R01 * Wy + R02 * Wz;
        const float nVy = Vy + R10 * Wx + R11 * Wy + R12 * Wz;
        const float nVz = Vz + R20 * Wx + R21 * Wy + R22 * Wz;
        float r0, r1, r2;
        r0 = R00 * S00 + R01 * S10 + R02 * S20;
        r1 = R00 * S01 + R01 * S11 + R02 * S21;
        r2 = R00 * S02 + R01 * S12 + R02 * S22;
        R00 = r0; R01 = r1; R02 = r2;
        r0 = R10 * S00 + R11 * S10 + R12 * S20;
        r1 = R10 * S01 + R11 * S11 + R12 * S21;
        r2 = R10 * S02 + R11 * S12 + R12 * S22;
        R10 = r0; R11 = r1; R12 = r2;
        r0 = R20 * S00 + R21 * S10 + R22 * S20;
        r1 = R20 * S01 + R21 * S11 + R22 * S21;
        r2 = R20 * S02 + R21 * S12 + R22 * S22;
        R20 = r0; R21 = r1; R22 = r2;

        Px = nPx; Py = nPy; Pz = nPz;
        Vx = nVx; Vy = nVy; Vz = nVz;
    }

    // cross-wave combine: wave 1 of each batch parks its state in LDS
    if (lane == 0 && half == 1) {
        float* s = stx[slot];
        s[0]=R00; s[1]=R01; s[2]=R02; s[3]=R10; s[4]=R11; s[5]=R12;
        s[6]=R20; s[7]=R21; s[8]=R22; s[9]=Vx; s[10]=Vy; s[11]=Vz;
        s[12]=Px; s[13]=Py; s[14]=Pz;
    }
    __syncthreads();

    if (tid == 0) {
        const float* s = stx[slot];
        const float S00=s[0],S01=s[1],S02=s[2],S10=s[3],S11=s[4],S12=s[5];
        const float S20=s[6],S21=s[7],S22=s[8],Wx=s[9],Wy=s[10],Wz=s[11];
        const float Qx=s[12],Qy=s[13],Qz=s[14];
        const float Tb = (float)(64 * CHUNK) * DT;

        const float nPx = Px + Vx * Tb + R00 * Qx + R01 * Qy + R02 * Qz;
        const float nPy = Py + Vy * Tb + R10 * Qx + R11 * Qy + R12 * Qz;
        const float nPz = Pz + Vz * Tb + R20 * Qx + R21 * Qy + R22 * Qz;
        float r0, r1, r2;
        r0 = R00 * S00 + R01 * S10 + R02 * S20;
        r1 = R00 * S01 + R01 * S11 + R02 * S21;
        r2 = R00 * S02 + R01 * S12 + R02 * S22;
        const float F00 = r0, F01 = r1, F02 = r2;
        r0 = R10 * S00 + R11 * S10 + R12 * S20;
        r1 = R10 * S01 + R11 * S11 + R12 * S21;
        r2 = R10 * S02 + R11 * S12 + R12 * S22;
        const float F10 = r0, F11 = r1, F12 = r2;
        r0 = R20 * S00 + R21 * S10 + R22 * S20;
        r1 = R20 * S01 + R21 * S11 + R22 * S21;
        r2 = R20 * S02 + R21 * S12 + R22 * S22;
        const float F20 = r0, F21 = r1, F22 = r2;

        const float tr = F00 + F11 + F22;
        float c = (tr - 1.0f) * 0.5f;
        c = fminf(fmaxf(c, -1.0f + 1e-7f), 1.0f - 1e-7f);
        const float angle = acosf(c);
        const float sden = fmaxf(2.0f * sinf(angle), 1e-12f);
        const float axx = (F21 - F12) / sden;
        const float ayy = (F02 - F20) / sden;
        const float azz = (F10 - F01) / sden;
        const float halfang = angle * 0.5f;
        const float sh = sinf(halfang), ch = cosf(halfang);
        float* o = out + (size_t)b * 7;
        o[0] = nPx; o[1] = nPy; o[2] = nPz;
        o[3] = ch;
        o[4] = axx * sh; o[5] = ayy * sh; o[6] = azz * sh;
    }
}

extern "C" void kernel_launch(void* const* d_in, const int* in_sizes, int n_in,
                              void* d_out, int out_size, void* d_ws, size_t ws_size,
                              hipStream_t stream)
{
    const float* in = (const float*)d_in[0];
    float* out = (float*)d_out;
    const int threads = 256;
    const int blocks = B_TOT / 2;   // 2048 blocks, 2 batches per block
    preint_kernel<<<blocks, threads, 0, stream>>>(in, out);
}

// Round 5
// 71.045 us; speedup vs baseline: 1.8383x; 1.8383x over previous
//
#include <hip/hip_runtime.h>
#include <math.h>

#define S_LEN 2048
#define B_TOT 4096
#define CHUNK 32                  // steps per lane (1 wave per batch)
#define PH_STEPS 2                // steps per phase -> 3 float4 per lane
#define N_PH (CHUNK / PH_STEPS)   // 16 phases
#define DEPTH 3                   // phases in flight (triple buffer)
constexpr float DT       = 1.0f / 200.0f;
constexpr float HALF_DT2 = DT * DT * 0.5f;

// One preintegration step applied to running segment state (R,V,P).
__device__ __forceinline__ void istep(
    float& R00, float& R01, float& R02,
    float& R10, float& R11, float& R12,
    float& R20, float& R21, float& R22,
    float& Vx, float& Vy, float& Vz,
    float& Px, float& Py, float& Pz,
    float wx, float wy, float wz, float ax, float ay, float az)
{
    const float ux = wx * DT, uy = wy * DT, uz = wz * DT;
    const float t2 = ux * ux + uy * uy + uz * uz;          // theta^2 (tiny)
    const float Ac = 1.0f + t2 * (-1.0f / 6.0f  + t2 * (1.0f / 120.0f));
    const float Bc = 0.5f + t2 * (-1.0f / 24.0f + t2 * (1.0f / 720.0f));

    const float K00 = 1.0f + Bc * (ux * ux - t2);
    const float K11 = 1.0f + Bc * (uy * uy - t2);
    const float K22 = 1.0f + Bc * (uz * uz - t2);
    const float bxy = Bc * ux * uy, bxz = Bc * ux * uz, byz = Bc * uy * uz;
    const float aux = Ac * ux, auy = Ac * uy, auz = Ac * uz;
    const float K01 = bxy - auz, K10 = bxy + auz;
    const float K02 = bxz + auy, K20 = bxz - auy;
    const float K12 = byz - aux, K21 = byz + aux;

    float r0, r1, r2;
    r0 = R00 * K00 + R01 * K10 + R02 * K20;
    r1 = R00 * K01 + R01 * K11 + R02 * K21;
    r2 = R00 * K02 + R01 * K12 + R02 * K22;
    R00 = r0; R01 = r1; R02 = r2;
    r0 = R10 * K00 + R11 * K10 + R12 * K20;
    r1 = R10 * K01 + R11 * K11 + R12 * K21;
    r2 = R10 * K02 + R11 * K12 + R12 * K22;
    R10 = r0; R11 = r1; R12 = r2;
    r0 = R20 * K00 + R21 * K10 + R22 * K20;
    r1 = R20 * K01 + R21 * K11 + R22 * K21;
    r2 = R20 * K02 + R21 * K12 + R22 * K22;
    R20 = r0; R21 = r1; R22 = r2;

    const float tx = R00 * ax + R01 * ay + R02 * az;
    const float ty = R10 * ax + R11 * ay + R12 * az;
    const float tz = R20 * ax + R21 * ay + R22 * az;
    Vx += tx * DT; Vy += ty * DT; Vz += tz * DT;
    Px += Vx * DT + tx * HALF_DT2;
    Py += Vy * DT + ty * HALF_DT2;
    Pz += Vz * DT + tz * HALF_DT2;
}

__device__ __forceinline__ void gload16(const float4* g, float4* l)
{
    // async global -> LDS, 16B per lane; LDS dest = wave-uniform base + lane*16
    __builtin_amdgcn_global_load_lds(
        (const __attribute__((address_space(1))) void*)g,
        (__attribute__((address_space(3))) void*)l,
        16, 0, 0);
}

// block = 256 threads = 4 waves = 4 batches (1 wave per batch).
// __launch_bounds__(256,4): VGPR cap 128 — proven spill-free shape (R3).
// LDS 36 KB/block -> 4 blocks/CU; 4 waves/SIMD.
// Depth-3 global_load_lds pipeline with counted vmcnt waits (T3/T4):
// 9 KB per wave stays in flight across the whole K-loop.
__global__ __launch_bounds__(256, 4)
void preint_kernel(const float* __restrict__ in, float* __restrict__ out)
{
    const int wv   = threadIdx.x >> 6;             // wave in block = batch slot
    const int b    = blockIdx.x * 4 + wv;
    const int lane = threadIdx.x & 63;

    // Per-wave triple buffer: 3 x 192 float4 (3 KiB each).
    // Slot s holds record (s/3)'s float4 #(s%3) of a phase -> record stride
    // 48 B, so the per-lane 3x ds_read_b128 tiles all 32 banks minimally.
    __shared__ float4 lds[4][DEPTH][192];

    // gather pointers: gload instruction m (0..2) fills slot m*64+lane;
    // record r = s/3, piece j = s%3; global float4 idx = r*48 + p*3 + j.
    const float4* g4 = reinterpret_cast<const float4*>(in) + (size_t)b * (S_LEN * 6 / 4);
    const float4 *gp0, *gp1, *gp2;
    {
        const int s0 = lane,       r0 = s0 / 3, j0 = s0 - 3 * r0;
        const int s1 = 64 + lane,  r1 = s1 / 3, j1 = s1 - 3 * r1;
        const int s2 = 128 + lane, r2 = s2 / 3, j2 = s2 - 3 * r2;
        gp0 = g4 + r0 * 48 + j0;
        gp1 = g4 + r1 * 48 + j1;
        gp2 = g4 + r2 * 48 + j2;
    }

    // prologue: stage phases 0..2 (9 loads outstanding)
    #pragma unroll
    for (int p = 0; p < DEPTH; ++p) {
        gload16(gp0, &lds[wv][p][0]);
        gload16(gp1, &lds[wv][p][64]);
        gload16(gp2, &lds[wv][p][128]);
        gp0 += 3; gp1 += 3; gp2 += 3;
    }

    float R00 = 1.f, R01 = 0.f, R02 = 0.f;
    float R10 = 0.f, R11 = 1.f, R12 = 0.f;
    float R20 = 0.f, R21 = 0.f, R22 = 1.f;
    float Vx = 0.f, Vy = 0.f, Vz = 0.f;
    float Px = 0.f, Py = 0.f, Pz = 0.f;

    const int rbase = lane * 3;
    int buf = 0;

    #pragma unroll 1
    for (int p = 0; p < N_PH; ++p) {
        // wait until phase p's 3 loads (oldest in queue) have landed:
        // outstanding <= 6 means phases p+1, p+2 may still be in flight.
        if (p < N_PH - 2)      asm volatile("s_waitcnt vmcnt(6)" ::: "memory");
        else if (p == N_PH - 2) asm volatile("s_waitcnt vmcnt(3)" ::: "memory");
        else                    asm volatile("s_waitcnt vmcnt(0)" ::: "memory");

        const float4* lb = &lds[wv][buf][0];
        const float4 q0 = lb[rbase];
        const float4 q1 = lb[rbase + 1];
        const float4 q2 = lb[rbase + 2];
        // drain ds_reads, then reuse this buffer for phase p+DEPTH
        asm volatile("s_waitcnt lgkmcnt(0)" ::: "memory");
        if (p < N_PH - DEPTH) {
            gload16(gp0, &lds[wv][buf][0]);
            gload16(gp1, &lds[wv][buf][64]);
            gload16(gp2, &lds[wv][buf][128]);
            gp0 += 3; gp1 += 3; gp2 += 3;
        }
        buf = (buf == DEPTH - 1) ? 0 : buf + 1;

        istep(R00,R01,R02,R10,R11,R12,R20,R21,R22,Vx,Vy,Vz,Px,Py,Pz,
              q0.x, q0.y, q0.z, q0.w, q1.x, q1.y);
        istep(R00,R01,R02,R10,R11,R12,R20,R21,R22,Vx,Vy,Vz,Px,Py,Pz,
              q1.z, q1.w, q2.x, q2.y, q2.z, q2.w);
    }

    // ordered tree reduction across the wave: lane i holds chunks [i, i+o)
    #pragma unroll
    for (int o = 1; o < 64; o <<= 1) {
        const float Tb = (float)(o * CHUNK) * DT;
        const float S00 = __shfl_down(R00, o, 64), S01 = __shfl_down(R01, o, 64), S02 = __shfl_down(R02, o, 64);
        const float S10 = __shfl_down(R10, o, 64), S11 = __shfl_down(R11, o, 64), S12 = __shfl_down(R12, o, 64);
        const float S20 = __shfl_down(R20, o, 64), S21 = __shfl_down(R21, o, 64), S22 = __shfl_down(R22, o, 64);
        const float Wx  = __shfl_down(Vx, o, 64),  Wy  = __shfl_down(Vy, o, 64),  Wz  = __shfl_down(Vz, o, 64);
        const float Qx  = __shfl_down(Px, o, 64),  Qy  = __shfl_down(Py, o, 64),  Qz  = __shfl_down(Pz, o, 64);

        const float nPx = Px + Vx * Tb + R00 * Qx + R01 * Qy + R02 * Qz;
        const float nPy = Py + Vy * Tb + R10 * Qx + R11 * Qy + R12 * Qz;
        const float nPz = Pz + Vz * Tb + R20 * Qx + R21 * Qy + R22 * Qz;
        const float nVx = Vx + R00 * Wx + R01 * Wy + R02 * Wz;
        const float nVy = Vy + R10 * Wx + R11 * Wy + R12 * Wz;
        const float nVz = Vz + R20 * Wx + R21 * Wy + R22 * Wz;
        float r0, r1, r2;
        r0 = R00 * S00 + R01 * S10 + R02 * S20;
        r1 = R00 * S01 + R01 * S11 + R02 * S21;
        r2 = R00 * S02 + R01 * S12 + R02 * S22;
        R00 = r0; R01 = r1; R02 = r2;
        r0 = R10 * S00 + R11 * S10 + R12 * S20;
        r1 = R10 * S01 + R11 * S11 + R12 * S21;
        r2 = R10 * S02 + R11 * S12 + R12 * S22;
        R10 = r0; R11 = r1; R12 = r2;
        r0 = R20 * S00 + R21 * S10 + R22 * S20;
        r1 = R20 * S01 + R21 * S11 + R22 * S21;
        r2 = R20 * S02 + R21 * S12 + R22 * S22;
        R20 = r0; R21 = r1; R22 = r2;

        Px = nPx; Py = nPy; Pz = nPz;
        Vx = nVx; Vy = nVy; Vz = nVz;
    }

    if (lane == 0) {
        const float tr = R00 + R11 + R22;
        float c = (tr - 1.0f) * 0.5f;
        c = fminf(fmaxf(c, -1.0f + 1e-7f), 1.0f - 1e-7f);
        const float angle = acosf(c);
        const float s = fmaxf(2.0f * sinf(angle), 1e-12f);
        const float axx = (R21 - R12) / s;
        const float ayy = (R02 - R20) / s;
        const float azz = (R10 - R01) / s;
        const float half = angle * 0.5f;
        const float sh = sinf(half), ch = cosf(half);
        float* o = out + (size_t)b * 7;
        o[0] = Px; o[1] = Py; o[2] = Pz;
        o[3] = ch;
        o[4] = axx * sh; o[5] = ayy * sh; o[6] = azz * sh;
    }
}

extern "C" void kernel_launch(void* const* d_in, const int* in_sizes, int n_in,
                              void* d_out, int out_size, void* d_ws, size_t ws_size,
                              hipStream_t stream)
{
    const float* in = (const float*)d_in[0];
    float* out = (float*)d_out;
    const int threads = 256;
    const int blocks = B_TOT / 4;   // 1024 blocks, 4 batches (waves) per block
    preint_kernel<<<blocks, threads, 0, stream>>>(in, out);
}

// Round 6
// 69.253 us; speedup vs baseline: 1.8858x; 1.0259x over previous
//
#include <hip/hip_runtime.h>
#include <math.h>

#define S_LEN 2048
#define B_TOT 4096
#define CHUNK 16                  // steps per thread; 128 threads (2 waves) per batch
#define PH_STEPS 2                // steps per phase -> 3 float4 per lane
#define N_PH (CHUNK / PH_STEPS)   // 8 phases
#define DEPTH 2                   // phases in flight (double buffer)
constexpr float DT       = 1.0f / 200.0f;
constexpr float HALF_DT2 = DT * DT * 0.5f;

// One preintegration step applied to running segment state (R,V,P).
__device__ __forceinline__ void istep(
    float& R00, float& R01, float& R02,
    float& R10, float& R11, float& R12,
    float& R20, float& R21, float& R22,
    float& Vx, float& Vy, float& Vz,
    float& Px, float& Py, float& Pz,
    float wx, float wy, float wz, float ax, float ay, float az)
{
    const float ux = wx * DT, uy = wy * DT, uz = wz * DT;
    const float t2 = ux * ux + uy * uy + uz * uz;          // theta^2 (tiny)
    const float Ac = 1.0f + t2 * (-1.0f / 6.0f  + t2 * (1.0f / 120.0f));
    const float Bc = 0.5f + t2 * (-1.0f / 24.0f + t2 * (1.0f / 720.0f));

    const float K00 = 1.0f + Bc * (ux * ux - t2);
    const float K11 = 1.0f + Bc * (uy * uy - t2);
    const float K22 = 1.0f + Bc * (uz * uz - t2);
    const float bxy = Bc * ux * uy, bxz = Bc * ux * uz, byz = Bc * uy * uz;
    const float aux = Ac * ux, auy = Ac * uy, auz = Ac * uz;
    const float K01 = bxy - auz, K10 = bxy + auz;
    const float K02 = bxz + auy, K20 = bxz - auy;
    const float K12 = byz - aux, K21 = byz + aux;

    float r0, r1, r2;
    r0 = R00 * K00 + R01 * K10 + R02 * K20;
    r1 = R00 * K01 + R01 * K11 + R02 * K21;
    r2 = R00 * K02 + R01 * K12 + R02 * K22;
    R00 = r0; R01 = r1; R02 = r2;
    r0 = R10 * K00 + R11 * K10 + R12 * K20;
    r1 = R10 * K01 + R11 * K11 + R12 * K21;
    r2 = R10 * K02 + R11 * K12 + R12 * K22;
    R10 = r0; R11 = r1; R12 = r2;
    r0 = R20 * K00 + R21 * K10 + R22 * K20;
    r1 = R20 * K01 + R21 * K11 + R22 * K21;
    r2 = R20 * K02 + R21 * K12 + R22 * K22;
    R20 = r0; R21 = r1; R22 = r2;

    const float tx = R00 * ax + R01 * ay + R02 * az;
    const float ty = R10 * ax + R11 * ay + R12 * az;
    const float tz = R20 * ax + R21 * ay + R22 * az;
    Vx += tx * DT; Vy += ty * DT; Vz += tz * DT;
    Px += Vx * DT + tx * HALF_DT2;
    Py += Vy * DT + ty * HALF_DT2;
    Pz += Vz * DT + tz * HALF_DT2;
}

__device__ __forceinline__ void gload16(const float4* g, float4* l)
{
    // async global -> LDS, 16B per lane; LDS dest = wave-uniform base + lane*16
    __builtin_amdgcn_global_load_lds(
        (const __attribute__((address_space(1))) void*)g,
        (__attribute__((address_space(3))) void*)l,
        16, 0, 0);
}

// block = 256 threads = 4 waves = 2 batches (2 waves per batch).
// __launch_bounds__(256, 4): empirically this yields a ~64-VGPR budget
// (hipcc's 2nd-arg formula is ~2x aggressive: (256,8) gave VGPR=32 + spill
// in R2/R4). Lean gload_lds structure fits ~50 live regs -> no spill.
// LDS 24.7 KB/block -> 6 blocks/CU -> 6 waves/SIMD (LDS-limited).
__global__ __launch_bounds__(256, 4)
void preint_kernel(const float* __restrict__ in, float* __restrict__ out)
{
    const int wv   = threadIdx.x >> 6;             // wave in block (0..3)
    const int slot = threadIdx.x >> 7;             // batch within block (0..1)
    const int b    = blockIdx.x * 2 + slot;
    const int tid  = threadIdx.x & 127;            // thread within batch
    const int lane = threadIdx.x & 63;
    const int half = (threadIdx.x >> 6) & 1;       // which wave of the batch

    // Per-wave double buffer: 2 x 192 float4 (3 KiB each). Slot s of a buffer
    // holds record (s/3)'s float4 #(s%3) of a phase -> record stride 48 B.
    __shared__ float4 lds[4][DEPTH][192];
    __shared__ float stx[2][15];                   // cross-wave combine

    // gather pointers: gload instruction m (0..2) fills slot m*64+lane;
    // record r = s/3 (this wave handles records half*64+r), piece j = s%3;
    // record length = 16 steps = 24 float4; global idx = rec*24 + p*3 + j.
    const float4* g4 = reinterpret_cast<const float4*>(in) + (size_t)b * (S_LEN * 6 / 4);
    const float4 *gp0, *gp1, *gp2;
    {
        const int s0 = lane,       r0 = s0 / 3, j0 = s0 - 3 * r0;
        const int s1 = 64 + lane,  r1 = s1 / 3, j1 = s1 - 3 * r1;
        const int s2 = 128 + lane, r2 = s2 / 3, j2 = s2 - 3 * r2;
        gp0 = g4 + (half * 64 + r0) * 24 + j0;
        gp1 = g4 + (half * 64 + r1) * 24 + j1;
        gp2 = g4 + (half * 64 + r2) * 24 + j2;
    }

    // prologue: stage phases 0 and 1 (6 loads outstanding)
    #pragma unroll
    for (int p = 0; p < DEPTH; ++p) {
        gload16(gp0, &lds[wv][p][0]);
        gload16(gp1, &lds[wv][p][64]);
        gload16(gp2, &lds[wv][p][128]);
        gp0 += 3; gp1 += 3; gp2 += 3;
    }

    float R00 = 1.f, R01 = 0.f, R02 = 0.f;
    float R10 = 0.f, R11 = 1.f, R12 = 0.f;
    float R20 = 0.f, R21 = 0.f, R22 = 1.f;
    float Vx = 0.f, Vy = 0.f, Vz = 0.f;
    float Px = 0.f, Py = 0.f, Pz = 0.f;

    const int rbase = lane * 3;
    int buf = 0;

    #pragma unroll 1
    for (int p = 0; p < N_PH; ++p) {
        // wait for phase p's 3 loads (oldest in queue); keep p+1's in flight
        if (p < N_PH - 1) asm volatile("s_waitcnt vmcnt(3)" ::: "memory");
        else              asm volatile("s_waitcnt vmcnt(0)" ::: "memory");

        const float4* lb = &lds[wv][buf][0];
        const float4 q0 = lb[rbase];
        const float4 q1 = lb[rbase + 1];
        const float4 q2 = lb[rbase + 2];
        // drain ds_reads, then reuse this buffer for phase p+DEPTH
        asm volatile("s_waitcnt lgkmcnt(0)" ::: "memory");
        if (p + DEPTH < N_PH) {
            gload16(gp0, &lds[wv][buf][0]);
            gload16(gp1, &lds[wv][buf][64]);
            gload16(gp2, &lds[wv][buf][128]);
            gp0 += 3; gp1 += 3; gp2 += 3;
        }
        buf ^= 1;

        istep(R00,R01,R02,R10,R11,R12,R20,R21,R22,Vx,Vy,Vz,Px,Py,Pz,
              q0.x, q0.y, q0.z, q0.w, q1.x, q1.y);
        istep(R00,R01,R02,R10,R11,R12,R20,R21,R22,Vx,Vy,Vz,Px,Py,Pz,
              q1.z, q1.w, q2.x, q2.y, q2.z, q2.w);
    }

    // ordered tree reduction across the wave: lane i holds chunks [i, i+o)
    #pragma unroll
    for (int o = 1; o < 64; o <<= 1) {
        const float Tb = (float)(o * CHUNK) * DT;
        const float S00 = __shfl_down(R00, o, 64), S01 = __shfl_down(R01, o, 64), S02 = __shfl_down(R02, o, 64);
        const float S10 = __shfl_down(R10, o, 64), S11 = __shfl_down(R11, o, 64), S12 = __shfl_down(R12, o, 64);
        const float S20 = __shfl_down(R20, o, 64), S21 = __shfl_down(R21, o, 64), S22 = __shfl_down(R22, o, 64);
        const float Wx  = __shfl_down(Vx, o, 64),  Wy  = __shfl_down(Vy, o, 64),  Wz  = __shfl_down(Vz, o, 64);
        const float Qx  = __shfl_down(Px, o, 64),  Qy  = __shfl_down(Py, o, 64),  Qz  = __shfl_down(Pz, o, 64);

        const float nPx = Px + Vx * Tb + R00 * Qx + R01 * Qy + R02 * Qz;
        const float nPy = Py + Vy * Tb + R10 * Qx + R11 * Qy + R12 * Qz;
        const float nPz = Pz + Vz * Tb + R20 * Qx + R21 * Qy + R22 * Qz;
        const float nVx = Vx + R00 * Wx + R01 * Wy + R02 * Wz;
        const float nVy = Vy + R10 * Wx + R11 * Wy + R12 * Wz;
        const float nVz = Vz + R20 * Wx + R21 * Wy + R22 * Wz;
        float r0, r1, r2;
        r0 = R00 * S00 + R01 * S10 + R02 * S20;
        r1 = R00 * S01 + R01 * S11 + R02 * S21;
        r2 = R00 * S02 + R01 * S12 + R02 * S22;
        R00 = r0; R01 = r1; R02 = r2;
        r0 = R10 * S00 + R11 * S10 + R12 * S20;
        r1 = R10 * S01 + R11 * S11 + R12 * S21;
        r2 = R10 * S02 + R11 * S12 + R12 * S22;
        R10 = r0; R11 = r1; R12 = r2;
        r0 = R20 * S00 + R21 * S10 + R22 * S20;
        r1 = R20 * S01 + R21 * S11 + R22 * S21;
        r2 = R20 * S02 + R21 * S12 + R22 * S22;
        R20 = r0; R21 = r1; R22 = r2;

        Px = nPx; Py = nPy; Pz = nPz;
        Vx = nVx; Vy = nVy; Vz = nVz;
    }

    // cross-wave combine: wave 1 of each batch parks its state in LDS
    if (lane == 0 && half == 1) {
        float* s = stx[slot];
        s[0]=R00; s[1]=R01; s[2]=R02; s[3]=R10; s[4]=R11; s[5]=R12;
        s[6]=R20; s[7]=R21; s[8]=R22; s[9]=Vx; s[10]=Vy; s[11]=Vz;
        s[12]=Px; s[13]=Py; s[14]=Pz;
    }
    __syncthreads();

    if (tid == 0) {
        const float* s = stx[slot];
        const float S00=s[0],S01=s[1],S02=s[2],S10=s[3],S11=s[4],S12=s[5];
        const float S20=s[6],S21=s[7],S22=s[8],Wx=s[9],Wy=s[10],Wz=s[11];
        const float Qx=s[12],Qy=s[13],Qz=s[14];
        const float Tb = (float)(64 * CHUNK) * DT;

        const float nPx = Px + Vx * Tb + R00 * Qx + R01 * Qy + R02 * Qz;
        const float nPy = Py + Vy * Tb + R10 * Qx + R11 * Qy + R12 * Qz;
        const float nPz = Pz + Vz * Tb + R20 * Qx + R21 * Qy + R22 * Qz;
        float r0, r1, r2;
        r0 = R00 * S00 + R01 * S10 + R02 * S20;
        r1 = R00 * S01 + R01 * S11 + R02 * S21;
        r2 = R00 * S02 + R01 * S12 + R02 * S22;
        const float F00 = r0, F01 = r1, F02 = r2;
        r0 = R10 * S00 + R11 * S10 + R12 * S20;
        r1 = R10 * S01 + R11 * S11 + R12 * S21;
        r2 = R10 * S02 + R11 * S12 + R12 * S22;
        const float F10 = r0, F11 = r1, F12 = r2;
        r0 = R20 * S00 + R21 * S10 + R22 * S20;
        r1 = R20 * S01 + R21 * S11 + R22 * S21;
        r2 = R20 * S02 + R21 * S12 + R22 * S22;
        const float F20 = r0, F21 = r1, F22 = r2;

        const float tr = F00 + F11 + F22;
        float c = (tr - 1.0f) * 0.5f;
        c = fminf(fmaxf(c, -1.0f + 1e-7f), 1.0f - 1e-7f);
        const float angle = acosf(c);
        const float sden = fmaxf(2.0f * sinf(angle), 1e-12f);
        const float axx = (F21 - F12) / sden;
        const float ayy = (F02 - F20) / sden;
        const float azz = (F10 - F01) / sden;
        const float halfang = angle * 0.5f;
        const float sh = sinf(halfang), ch = cosf(halfang);
        float* o = out + (size_t)b * 7;
        o[0] = nPx; o[1] = nPy; o[2] = nPz;
        o[3] = ch;
        o[4] = axx * sh; o[5] = ayy * sh; o[6] = azz * sh;
    }
}

extern "C" void kernel_launch(void* const* d_in, const int* in_sizes, int n_in,
                              void* d_out, int out_size, void* d_ws, size_t ws_size,
                              hipStream_t stream)
{
    const float* in = (const float*)d_in[0];
    float* out = (float*)d_out;
    const int threads = 256;
    const int blocks = B_TOT / 2;   // 2048 blocks, 2 batches per block
    preint_kernel<<<blocks, threads, 0, stream>>>(in, out);
}

// Round 8
// 51.034 us; speedup vs baseline: 2.5591x; 1.3570x over previous
//
#include <hip/hip_runtime.h>
#include <math.h>

#define S_LEN 2048
#define B_TOT 4096
#define CHUNK 16                  // steps per thread; 128 threads (2 waves) per batch
constexpr float DT       = 1.0f / 200.0f;
constexpr float HALF_DT2 = DT * DT * 0.5f;

// One preintegration step applied to running segment state (R,V,P).
__device__ __forceinline__ void istep(
    float& R00, float& R01, float& R02,
    float& R10, float& R11, float& R12,
    float& R20, float& R21, float& R22,
    float& Vx, float& Vy, float& Vz,
    float& Px, float& Py, float& Pz,
    float wx, float wy, float wz, float ax, float ay, float az)
{
    const float ux = wx * DT, uy = wy * DT, uz = wz * DT;
    const float t2 = ux * ux + uy * uy + uz * uz;          // theta^2 (tiny)
    const float Ac = 1.0f + t2 * (-1.0f / 6.0f  + t2 * (1.0f / 120.0f));
    const float Bc = 0.5f + t2 * (-1.0f / 24.0f + t2 * (1.0f / 720.0f));

    const float K00 = 1.0f + Bc * (ux * ux - t2);
    const float K11 = 1.0f + Bc * (uy * uy - t2);
    const float K22 = 1.0f + Bc * (uz * uz - t2);
    const float bxy = Bc * ux * uy, bxz = Bc * ux * uz, byz = Bc * uy * uz;
    const float aux = Ac * ux, auy = Ac * uy, auz = Ac * uz;
    const float K01 = bxy - auz, K10 = bxy + auz;
    const float K02 = bxz + auy, K20 = bxz - auy;
    const float K12 = byz - aux, K21 = byz + aux;

    float r0, r1, r2;
    r0 = R00 * K00 + R01 * K10 + R02 * K20;
    r1 = R00 * K01 + R01 * K11 + R02 * K21;
    r2 = R00 * K02 + R01 * K12 + R02 * K22;
    R00 = r0; R01 = r1; R02 = r2;
    r0 = R10 * K00 + R11 * K10 + R12 * K20;
    r1 = R10 * K01 + R11 * K11 + R12 * K21;
    r2 = R10 * K02 + R11 * K12 + R12 * K22;
    R10 = r0; R11 = r1; R12 = r2;
    r0 = R20 * K00 + R21 * K10 + R22 * K20;
    r1 = R20 * K01 + R21 * K11 + R22 * K21;
    r2 = R20 * K02 + R21 * K12 + R22 * K22;
    R20 = r0; R21 = r1; R22 = r2;

    const float tx = R00 * ax + R01 * ay + R02 * az;
    const float ty = R10 * ax + R11 * ay + R12 * az;
    const float tz = R20 * ax + R21 * ay + R22 * az;
    Vx += tx * DT; Vy += ty * DT; Vz += tz * DT;
    Px += Vx * DT + tx * HALF_DT2;
    Py += Vy * DT + ty * HALF_DT2;
    Pz += Vz * DT + tz * HALF_DT2;
}

// block = 256 threads = 4 waves = 2 batches (2 waves per batch); 2048 blocks
// = 8192 waves = exactly 8 waves/SIMD. No LDS staging (race-free): each lane
// streams its own 384B record via 24 float4 loads, depth-2 phase prefetch in
// registers with even/odd buffer roles (no reg moves). Live set ~50 regs;
// (256,4) caps VGPR at 64 ((256,8) clamps to 32 and spills — R2/R4).
__global__ __launch_bounds__(256, 4)
void preint_kernel(const float* __restrict__ in, float* __restrict__ out)
{
    const int slot = threadIdx.x >> 7;             // batch within block (0..1)
    const int b    = blockIdx.x * 2 + slot;
    const int tid  = threadIdx.x & 127;            // thread within batch = record
    const int lane = threadIdx.x & 63;
    const int half = (threadIdx.x >> 6) & 1;       // which wave of the batch

    __shared__ float stx[2][15];                   // cross-wave combine only

    // record = 16 steps = 96 floats = 24 float4, base = rec*24
    const float4* gp = reinterpret_cast<const float4*>(in)
                     + (size_t)b * (S_LEN * 6 / 4) + (size_t)tid * 24;

    // prologue: phases 0 and 1 in registers
    float4 a0 = gp[0], a1 = gp[1], a2 = gp[2];
    float4 b0 = gp[3], b1 = gp[4], b2 = gp[5];

    float R00 = 1.f, R01 = 0.f, R02 = 0.f;
    float R10 = 0.f, R11 = 1.f, R12 = 0.f;
    float R20 = 0.f, R21 = 0.f, R22 = 1.f;
    float Vx = 0.f, Vy = 0.f, Vz = 0.f;
    float Px = 0.f, Py = 0.f, Pz = 0.f;

    // 8 phases of 2 steps; even phase consumes {a}, odd consumes {b};
    // refills issue ~1.5 phases ahead of consumption.
    #pragma unroll 1
    for (int p = 0; p < 8; p += 2) {
        istep(R00,R01,R02,R10,R11,R12,R20,R21,R22,Vx,Vy,Vz,Px,Py,Pz,
              a0.x, a0.y, a0.z, a0.w, a1.x, a1.y);
        istep(R00,R01,R02,R10,R11,R12,R20,R21,R22,Vx,Vy,Vz,Px,Py,Pz,
              a1.z, a1.w, a2.x, a2.y, a2.z, a2.w);
        if (p < 6) { a0 = gp[6]; a1 = gp[7]; a2 = gp[8]; }

        istep(R00,R01,R02,R10,R11,R12,R20,R21,R22,Vx,Vy,Vz,Px,Py,Pz,
              b0.x, b0.y, b0.z, b0.w, b1.x, b1.y);
        istep(R00,R01,R02,R10,R11,R12,R20,R21,R22,Vx,Vy,Vz,Px,Py,Pz,
              b1.z, b1.w, b2.x, b2.y, b2.z, b2.w);
        if (p < 6) { b0 = gp[9]; b1 = gp[10]; b2 = gp[11]; gp += 6; }
    }

    // ordered tree reduction across the wave: lane i holds chunks [i, i+o)
    #pragma unroll
    for (int o = 1; o < 64; o <<= 1) {
        const float Tb = (float)(o * CHUNK) * DT;
        const float S00 = __shfl_down(R00, o, 64), S01 = __shfl_down(R01, o, 64), S02 = __shfl_down(R02, o, 64);
        const float S10 = __shfl_down(R10, o, 64), S11 = __shfl_down(R11, o, 64), S12 = __shfl_down(R12, o, 64);
        const float S20 = __shfl_down(R20, o, 64), S21 = __shfl_down(R21, o, 64), S22 = __shfl_down(R22, o, 64);
        const float Wx  = __shfl_down(Vx, o, 64),  Wy  = __shfl_down(Vy, o, 64),  Wz  = __shfl_down(Vz, o, 64);
        const float Qx  = __shfl_down(Px, o, 64),  Qy  = __shfl_down(Py, o, 64),  Qz  = __shfl_down(Pz, o, 64);

        const float nPx = Px + Vx * Tb + R00 * Qx + R01 * Qy + R02 * Qz;
        const float nPy = Py + Vy * Tb + R10 * Qx + R11 * Qy + R12 * Qz;
        const float nPz = Pz + Vz * Tb + R20 * Qx + R21 * Qy + R22 * Qz;
        const float nVx = Vx + R00 * Wx + R01 * Wy + R02 * Wz;
        const float nVy = Vy + R10 * Wx + R11 * Wy + R12 * Wz;
        const float nVz = Vz + R20 * Wx + R21 * Wy + R22 * Wz;
        float r0, r1, r2;
        r0 = R00 * S00 + R01 * S10 + R02 * S20;
        r1 = R00 * S01 + R01 * S11 + R02 * S21;
        r2 = R00 * S02 + R01 * S12 + R02 * S22;
        R00 = r0; R01 = r1; R02 = r2;
        r0 = R10 * S00 + R11 * S10 + R12 * S20;
        r1 = R10 * S01 + R11 * S11 + R12 * S21;
        r2 = R10 * S02 + R11 * S12 + R12 * S22;
        R10 = r0; R11 = r1; R12 = r2;
        r0 = R20 * S00 + R21 * S10 + R22 * S20;
        r1 = R20 * S01 + R21 * S11 + R22 * S21;
        r2 = R20 * S02 + R21 * S12 + R22 * S22;
        R20 = r0; R21 = r1; R22 = r2;

        Px = nPx; Py = nPy; Pz = nPz;
        Vx = nVx; Vy = nVy; Vz = nVz;
    }

    // cross-wave combine: wave 1 of each batch parks its state in LDS
    if (lane == 0 && half == 1) {
        float* s = stx[slot];
        s[0]=R00; s[1]=R01; s[2]=R02; s[3]=R10; s[4]=R11; s[5]=R12;
        s[6]=R20; s[7]=R21; s[8]=R22; s[9]=Vx; s[10]=Vy; s[11]=Vz;
        s[12]=Px; s[13]=Py; s[14]=Pz;
    }
    __syncthreads();

    if (tid == 0) {
        const float* s = stx[slot];
        const float S00=s[0],S01=s[1],S02=s[2],S10=s[3],S11=s[4],S12=s[5];
        const float S20=s[6],S21=s[7],S22=s[8],Wx=s[9],Wy=s[10],Wz=s[11];
        const float Qx=s[12],Qy=s[13],Qz=s[14];
        const float Tb = (float)(64 * CHUNK) * DT;

        const float nPx = Px + Vx * Tb + R00 * Qx + R01 * Qy + R02 * Qz;
        const float nPy = Py + Vy * Tb + R10 * Qx + R11 * Qy + R12 * Qz;
        const float nPz = Pz + Vz * Tb + R20 * Qx + R21 * Qy + R22 * Qz;
        float r0, r1, r2;
        r0 = R00 * S00 + R01 * S10 + R02 * S20;
        r1 = R00 * S01 + R01 * S11 + R02 * S21;
        r2 = R00 * S02 + R01 * S12 + R02 * S22;
        const float F00 = r0, F01 = r1, F02 = r2;
        r0 = R10 * S00 + R11 * S10 + R12 * S20;
        r1 = R10 * S01 + R11 * S11 + R12 * S21;
        r2 = R10 * S02 + R11 * S12 + R12 * S22;
        const float F10 = r0, F11 = r1, F12 = r2;
        r0 = R20 * S00 + R21 * S10 + R22 * S20;
        r1 = R20 * S01 + R21 * S11 + R22 * S21;
        r2 = R20 * S02 + R21 * S12 + R22 * S22;
        const float F20 = r0, F21 = r1, F22 = r2;

        const float tr = F00 + F11 + F22;
        float c = (tr - 1.0f) * 0.5f;
        c = fminf(fmaxf(c, -1.0f + 1e-7f), 1.0f - 1e-7f);
        const float angle = acosf(c);
        const float sden = fmaxf(2.0f * sinf(angle), 1e-12f);
        const float axx = (F21 - F12) / sden;
        const float ayy = (F02 - F20) / sden;
        const float azz = (F10 - F01) / sden;
        const float halfang = angle * 0.5f;
        const float sh = sinf(halfang), ch = cosf(halfang);
        float* o = out + (size_t)b * 7;
        o[0] = nPx; o[1] = nPy; o[2] = nPz;
        o[3] = ch;
        o[4] = axx * sh; o[5] = ayy * sh; o[6] = azz * sh;
    }
}

extern "C" void kernel_launch(void* const* d_in, const int* in_sizes, int n_in,
                              void* d_out, int out_size, void* d_ws, size_t ws_size,
                              hipStream_t stream)
{
    const float* in = (const float*)d_in[0];
    float* out = (float*)d_out;
    const int threads = 256;
    const int blocks = B_TOT / 2;   // 2048 blocks, 2 batches per block
    preint_kernel<<<blocks, threads, 0, stream>>>(in, out);
}

// Round 9
// 46.438 us; speedup vs baseline: 2.8123x; 1.0990x over previous
//
#include <hip/hip_runtime.h>
#include <math.h>

#define S_LEN 2048
#define B_TOT 4096
#define CHUNK 16                  // steps per thread; 128 threads (2 waves) per batch
constexpr float DT       = 1.0f / 200.0f;
constexpr float HALF_DT2 = DT * DT * 0.5f;

// One preintegration step applied to running segment state (R,V,P).
__device__ __forceinline__ void istep(
    float& R00, float& R01, float& R02,
    float& R10, float& R11, float& R12,
    float& R20, float& R21, float& R22,
    float& Vx, float& Vy, float& Vz,
    float& Px, float& Py, float& Pz,
    float wx, float wy, float wz, float ax, float ay, float az)
{
    const float ux = wx * DT, uy = wy * DT, uz = wz * DT;
    const float t2 = ux * ux + uy * uy + uz * uz;          // theta^2 (tiny)
    const float Ac = 1.0f + t2 * (-1.0f / 6.0f  + t2 * (1.0f / 120.0f));
    const float Bc = 0.5f + t2 * (-1.0f / 24.0f + t2 * (1.0f / 720.0f));

    const float K00 = 1.0f + Bc * (ux * ux - t2);
    const float K11 = 1.0f + Bc * (uy * uy - t2);
    const float K22 = 1.0f + Bc * (uz * uz - t2);
    const float bxy = Bc * ux * uy, bxz = Bc * ux * uz, byz = Bc * uy * uz;
    const float aux = Ac * ux, auy = Ac * uy, auz = Ac * uz;
    const float K01 = bxy - auz, K10 = bxy + auz;
    const float K02 = bxz + auy, K20 = bxz - auy;
    const float K12 = byz - aux, K21 = byz + aux;

    float r0, r1, r2;
    r0 = R00 * K00 + R01 * K10 + R02 * K20;
    r1 = R00 * K01 + R01 * K11 + R02 * K21;
    r2 = R00 * K02 + R01 * K12 + R02 * K22;
    R00 = r0; R01 = r1; R02 = r2;
    r0 = R10 * K00 + R11 * K10 + R12 * K20;
    r1 = R10 * K01 + R11 * K11 + R12 * K21;
    r2 = R10 * K02 + R11 * K12 + R12 * K22;
    R10 = r0; R11 = r1; R12 = r2;
    r0 = R20 * K00 + R21 * K10 + R22 * K20;
    r1 = R20 * K01 + R21 * K11 + R22 * K21;
    r2 = R20 * K02 + R21 * K12 + R22 * K22;
    R20 = r0; R21 = r1; R22 = r2;

    const float tx = R00 * ax + R01 * ay + R02 * az;
    const float ty = R10 * ax + R11 * ay + R12 * az;
    const float tz = R20 * ax + R21 * ay + R22 * az;
    Vx += tx * DT; Vy += ty * DT; Vz += tz * DT;
    Px += Vx * DT + tx * HALF_DT2;
    Py += Vy * DT + ty * HALF_DT2;
    Pz += Vz * DT + tz * HALF_DT2;
}

// block = 256 = 4 waves = 2 batches (2 waves/batch); 2048 blocks.
// Wave-cooperative COALESCED staging: round = 12 float4/record; instr m
// loads slot m*64+lane -> (rec=s/12, j=s%12); per-record 192B contiguous
// segments => ~16-18 lines per wave instruction (vs 64 scattered in R8).
// LDS record stride 13 float4 (52 dw, odd/4) => conflict-free b128 reads.
// Round-2 loads issue BEFORE round-1 consume (latency hidden under 8 steps).
// Fences at every LDS write<->read transition (R7 race lesson).
// (256,2) caps VGPR at 128 (empirical formula 256/N: R2/R4 (256,8)->32).
__global__ __launch_bounds__(256, 2)
void preint_kernel(const float* __restrict__ in, float* __restrict__ out)
{
    const int slot = threadIdx.x >> 7;             // batch within block (0..1)
    const int b    = blockIdx.x * 2 + slot;
    const int tid  = threadIdx.x & 127;            // thread within batch = record
    const int lane = threadIdx.x & 63;
    const int half = (threadIdx.x >> 6) & 1;       // which wave of the batch
    const int wv   = threadIdx.x >> 6;             // wave within block

    __shared__ float4 lds[4][64 * 13];             // 53248 B, per-wave private
    __shared__ float stx[2][15];                   // cross-wave combine

    const float4* g4 = reinterpret_cast<const float4*>(in) + (size_t)b * (S_LEN * 6 / 4);

    // staging maps (unrolled -> registers, all statically indexed)
    int goff[12], loff[12];
    #pragma unroll
    for (int m = 0; m < 12; ++m) {
        const int s   = m * 64 + lane;
        const int rec = s / 12;                    // magic-mul, compile-time const divisor
        const int j   = s - 12 * rec;
        goff[m] = (half * 64 + rec) * 24 + j;      // record = 24 float4; +12 for round 2
        loff[m] = rec * 13 + j;                    // padded LDS stride
    }
    float4* L = &lds[wv][0];
    const int rbase = lane * 13;

    // ---- stage round 1 (coalesced) ----
    float4 v[12];
    #pragma unroll
    for (int m = 0; m < 12; ++m) v[m] = g4[goff[m]];
    #pragma unroll
    for (int m = 0; m < 12; ++m) L[loff[m]] = v[m];    // compiler waits vmcnt per reg

    // ---- issue round 2 loads early (hide under round-1 consume) ----
    #pragma unroll
    for (int m = 0; m < 12; ++m) v[m] = g4[goff[m] + 12];

    asm volatile("s_waitcnt lgkmcnt(0)" ::: "memory"); // round-1 writes visible
    __builtin_amdgcn_sched_barrier(0);

    float R00 = 1.f, R01 = 0.f, R02 = 0.f;
    float R10 = 0.f, R11 = 1.f, R12 = 0.f;
    float R20 = 0.f, R21 = 0.f, R22 = 1.f;
    float Vx = 0.f, Vy = 0.f, Vz = 0.f;
    float Px = 0.f, Py = 0.f, Pz = 0.f;

    // ---- consume round 1: 8 steps (4 triplets) ----
    #pragma unroll
    for (int t = 0; t < 4; ++t) {
        const float4 q0 = L[rbase + 3 * t];
        const float4 q1 = L[rbase + 3 * t + 1];
        const float4 q2 = L[rbase + 3 * t + 2];
        istep(R00,R01,R02,R10,R11,R12,R20,R21,R22,Vx,Vy,Vz,Px,Py,Pz,
              q0.x, q0.y, q0.z, q0.w, q1.x, q1.y);
        istep(R00,R01,R02,R10,R11,R12,R20,R21,R22,Vx,Vy,Vz,Px,Py,Pz,
              q1.z, q1.w, q2.x, q2.y, q2.z, q2.w);
    }

    asm volatile("s_waitcnt lgkmcnt(0)" ::: "memory"); // round-1 reads drained
    __builtin_amdgcn_sched_barrier(0);

    // ---- stage round 2 into same buffer ----
    #pragma unroll
    for (int m = 0; m < 12; ++m) L[loff[m]] = v[m];

    asm volatile("s_waitcnt lgkmcnt(0)" ::: "memory"); // round-2 writes visible
    __builtin_amdgcn_sched_barrier(0);

    // ---- consume round 2 ----
    #pragma unroll
    for (int t = 0; t < 4; ++t) {
        const float4 q0 = L[rbase + 3 * t];
        const float4 q1 = L[rbase + 3 * t + 1];
        const float4 q2 = L[rbase + 3 * t + 2];
        istep(R00,R01,R02,R10,R11,R12,R20,R21,R22,Vx,Vy,Vz,Px,Py,Pz,
              q0.x, q0.y, q0.z, q0.w, q1.x, q1.y);
        istep(R00,R01,R02,R10,R11,R12,R20,R21,R22,Vx,Vy,Vz,Px,Py,Pz,
              q1.z, q1.w, q2.x, q2.y, q2.z, q2.w);
    }

    // ordered tree reduction across the wave: lane i holds chunks [i, i+o)
    #pragma unroll
    for (int o = 1; o < 64; o <<= 1) {
        const float Tb = (float)(o * CHUNK) * DT;
        const float S00 = __shfl_down(R00, o, 64), S01 = __shfl_down(R01, o, 64), S02 = __shfl_down(R02, o, 64);
        const float S10 = __shfl_down(R10, o, 64), S11 = __shfl_down(R11, o, 64), S12 = __shfl_down(R12, o, 64);
        const float S20 = __shfl_down(R20, o, 64), S21 = __shfl_down(R21, o, 64), S22 = __shfl_down(R22, o, 64);
        const float Wx  = __shfl_down(Vx, o, 64),  Wy  = __shfl_down(Vy, o, 64),  Wz  = __shfl_down(Vz, o, 64);
        const float Qx  = __shfl_down(Px, o, 64),  Qy  = __shfl_down(Py, o, 64),  Qz  = __shfl_down(Pz, o, 64);

        const float nPx = Px + Vx * Tb + R00 * Qx + R01 * Qy + R02 * Qz;
        const float nPy = Py + Vy * Tb + R10 * Qx + R11 * Qy + R12 * Qz;
        const float nPz = Pz + Vz * Tb + R20 * Qx + R21 * Qy + R22 * Qz;
        const float nVx = Vx + R00 * Wx + R01 * Wy + R02 * Wz;
        const float nVy = Vy + R10 * Wx + R11 * Wy + R12 * Wz;
        const float nVz = Vz + R20 * Wx + R21 * Wy + R22 * Wz;
        float r0, r1, r2;
        r0 = R00 * S00 + R01 * S10 + R02 * S20;
        r1 = R00 * S01 + R01 * S11 + R02 * S21;
        r2 = R00 * S02 + R01 * S12 + R02 * S22;
        R00 = r0; R01 = r1; R02 = r2;
        r0 = R10 * S00 + R11 * S10 + R12 * S20;
        r1 = R10 * S01 + R11 * S11 + R12 * S21;
        r2 = R10 * S02 + R11 * S12 + R12 * S22;
        R10 = r0; R11 = r1; R12 = r2;
        r0 = R20 * S00 + R21 * S10 + R22 * S20;
        r1 = R20 * S01 + R21 * S11 + R22 * S21;
        r2 = R20 * S02 + R21 * S12 + R22 * S22;
        R20 = r0; R21 = r1; R22 = r2;

        Px = nPx; Py = nPy; Pz = nPz;
        Vx = nVx; Vy = nVy; Vz = nVz;
    }

    // cross-wave combine: wave 1 of each batch parks its state in LDS
    if (lane == 0 && half == 1) {
        float* s = stx[slot];
        s[0]=R00; s[1]=R01; s[2]=R02; s[3]=R10; s[4]=R11; s[5]=R12;
        s[6]=R20; s[7]=R21; s[8]=R22; s[9]=Vx; s[10]=Vy; s[11]=Vz;
        s[12]=Px; s[13]=Py; s[14]=Pz;
    }
    __syncthreads();

    if (tid == 0) {
        const float* s = stx[slot];
        const float S00=s[0],S01=s[1],S02=s[2],S10=s[3],S11=s[4],S12=s[5];
        const float S20=s[6],S21=s[7],S22=s[8],Wx=s[9],Wy=s[10],Wz=s[11];
        const float Qx=s[12],Qy=s[13],Qz=s[14];
        const float Tb = (float)(64 * CHUNK) * DT;

        const float nPx = Px + Vx * Tb + R00 * Qx + R01 * Qy + R02 * Qz;
        const float nPy = Py + Vy * Tb + R10 * Qx + R11 * Qy + R12 * Qz;
        const float nPz = Pz + Vz * Tb + R20 * Qx + R21 * Qy + R22 * Qz;
        float r0, r1, r2;
        r0 = R00 * S00 + R01 * S10 + R02 * S20;
        r1 = R00 * S01 + R01 * S11 + R02 * S21;
        r2 = R00 * S02 + R01 * S12 + R02 * S22;
        const float F00 = r0, F01 = r1, F02 = r2;
        r0 = R10 * S00 + R11 * S10 + R12 * S20;
        r1 = R10 * S01 + R11 * S11 + R12 * S21;
        r2 = R10 * S02 + R11 * S12 + R12 * S22;
        const float F10 = r0, F11 = r1, F12 = r2;
        r0 = R20 * S00 + R21 * S10 + R22 * S20;
        r1 = R20 * S01 + R21 * S11 + R22 * S21;
        r2 = R20 * S02 + R21 * S12 + R22 * S22;
        const float F20 = r0, F21 = r1, F22 = r2;

        const float tr = F00 + F11 + F22;
        float c = (tr - 1.0f) * 0.5f;
        c = fminf(fmaxf(c, -1.0f + 1e-7f), 1.0f - 1e-7f);
        const float angle = acosf(c);
        const float sden = fmaxf(2.0f * sinf(angle), 1e-12f);
        const float axx = (F21 - F12) / sden;
        const float ayy = (F02 - F20) / sden;
        const float azz = (F10 - F01) / sden;
        const float halfang = angle * 0.5f;
        const float sh = sinf(halfang), ch = cosf(halfang);
        float* o = out + (size_t)b * 7;
        o[0] = nPx; o[1] = nPy; o[2] = nPz;
        o[3] = ch;
        o[4] = axx * sh; o[5] = ayy * sh; o[6] = azz * sh;
    }
}

extern "C" void kernel_launch(void* const* d_in, const int* in_sizes, int n_in,
                              void* d_out, int out_size, void* d_ws, size_t ws_size,
                              hipStream_t stream)
{
    const float* in = (const float*)d_in[0];
    float* out = (float*)d_out;
    const int threads = 256;
    const int blocks = B_TOT / 2;   // 2048 blocks, 2 batches per block
    preint_kernel<<<blocks, threads, 0, stream>>>(in, out);
}